// Round 18
// baseline (15.933 us; speedup 1.0000x reference)
//
#include <hip/hip_runtime.h>
#include <hip/hip_bf16.h>

// Problem constants (from reference)
#define NB      2048     // batch
#define RR      32       // rank per table
#define H_INIT  256
#define D_INIT  96
#define H_DYN   512
#define D_DYN   98
#define PCOLS   768      // H_INIT + H_DYN

#define LAM 2.8853900817779268f   // 2*log2(e): tanh(y) = 1 - 2/(exp2(LAM*y)+1)

typedef __attribute__((ext_vector_type(8))) short  short8;   // 8 bf16 (4 VGPRs)
typedef __attribute__((ext_vector_type(4))) float  f32x4;    // MFMA accum

__device__ __forceinline__ float fexp2(float x) {
#if __has_builtin(__builtin_amdgcn_exp2f)
    return __builtin_amdgcn_exp2f(x);
#else
    return exp2f(x);
#endif
}

// Wave64 sum -> uniform scalar. DPP row-scan + row_bcast; lands in lane 63.
// (proven rounds 1-17)
__device__ __forceinline__ float wave_total(float v) {
    v += __int_as_float(__builtin_amdgcn_update_dpp(0, __float_as_int(v), 0x111, 0xf, 0xf, false));
    v += __int_as_float(__builtin_amdgcn_update_dpp(0, __float_as_int(v), 0x112, 0xf, 0xf, false));
    v += __int_as_float(__builtin_amdgcn_update_dpp(0, __float_as_int(v), 0x114, 0xf, 0xf, false));
    v += __int_as_float(__builtin_amdgcn_update_dpp(0, __float_as_int(v), 0x118, 0xf, 0xf, false));
    v += __int_as_float(__builtin_amdgcn_update_dpp(0, __float_as_int(v), 0x142, 0xa, 0xf, false));
    v += __int_as_float(__builtin_amdgcn_update_dpp(0, __float_as_int(v), 0x143, 0xc, 0xf, false));
    return __int_as_float(__builtin_amdgcn_readlane(__float_as_int(v), 63));
}

// ---------------------------------------------------------------------------
// K_GEMM: R13 VERBATIM — frozen (every retile/stream variant regressed).
// ---------------------------------------------------------------------------
__global__ __launch_bounds__(512) void k_gemm(
    const int* __restrict__ idx,
    const float* __restrict__ U0, const float* __restrict__ U1, const float* __restrict__ U2,
    const float* __restrict__ Wi1, const float* __restrict__ bi1,
    const float* __restrict__ Wd1, const float* __restrict__ bd1,
    const float* __restrict__ Wd2,
    float* __restrict__ P,
    float* __restrict__ At, float* __restrict__ Ct, float* __restrict__ W2m2t)
{
    const int b   = blockIdx.x;
    const int tid = threadIdx.x;

    if (b == 256) {                        // RK4-constant transpose block
        const int j = tid;                 // 0..511
        At[j]    = LAM * Wd1[j * D_DYN + 0];
        Ct[j]    = LAM * Wd1[j * D_DYN + 1];
        W2m2t[j] = -2.f * Wd2[j];
        return;
    }

    __shared__ __align__(16) ushort As[3 * 64 * 32];   // [ks][item][k] 12 KB
    __shared__ __align__(16) ushort Bs[3 * 96 * 32];   // [ks][unit][k] 18 KB
    __shared__ int idx_s[64 * 3];

    const int ib    = b >> 3;              // 0..31 item tile
    const int jb    = b & 7;               // 0..7  unit tile
    const int item0 = ib * 64;
    const int unit0 = jb * 96;

    if (tid < 192) idx_s[tid] = idx[item0 * 3 + tid];
    __syncthreads();

    // ---- A stage: 3072 float2 -> 6 per thread ----
    #pragma unroll
    for (int p = 0; p < 6; ++p) {
        int e2  = tid + 512 * p;
        int ks  = e2 >> 10;
        int rem = e2 & 1023;
        int i   = rem >> 4, m = rem & 15;
        const float* __restrict__ U = (ks == 0) ? U0 : (ks == 1) ? U1 : U2;
        float2 v = *(const float2*)&U[idx_s[i * 3 + ks] * RR + 2 * m];
        *(__hip_bfloat162*)&As[ks * 2048 + i * 32 + 2 * m] = __float22bfloat162_rn(v);
    }
    // ---- B stage: 4608 float2 -> 9 per thread (panel stride 3072) ----
    #pragma unroll
    for (int p = 0; p < 9; ++p) {
        int e2  = tid + 512 * p;
        int ks  = e2 / 1536;
        int rem = e2 - ks * 1536;
        int j   = rem >> 4, m = rem & 15;
        int gu  = unit0 + j;
        const float* __restrict__ src = (gu < H_INIT)
            ? &Wi1[gu * D_INIT + ks * 32 + 2 * m]
            : &Wd1[(gu - H_INIT) * D_DYN + 2 + ks * 32 + 2 * m];
        float2 v = *(const float2*)src;
        *(__hip_bfloat162*)&Bs[ks * 3072 + j * 32 + 2 * m] = __float22bfloat162_rn(v);
    }
    __syncthreads();

    // ---- MFMA: wave (mw,nw) -> 16 items x 48 units ----
    const int lane  = tid & 63;
    const int w     = tid >> 6;
    const int mw    = w >> 1;              // 0..3
    const int nw    = w & 1;               // 0..1
    const int frow  = lane & 15;
    const int koff8 = (lane >> 4) * 8;

    short8 afr[3];
    #pragma unroll
    for (int ks = 0; ks < 3; ++ks)
        afr[ks] = *(const short8*)&As[ks * 2048 + (mw * 16 + frow) * 32 + koff8];

    f32x4 acc[3];
    #pragma unroll
    for (int nt = 0; nt < 3; ++nt) acc[nt] = (f32x4){0.f, 0.f, 0.f, 0.f};
    #pragma unroll
    for (int nt = 0; nt < 3; ++nt) {
        const int brow = nw * 48 + nt * 16 + frow;
        #pragma unroll
        for (int ks = 0; ks < 3; ++ks) {
            short8 bfr = *(const short8*)&Bs[ks * 3072 + brow * 32 + koff8];
            acc[nt] = __builtin_amdgcn_mfma_f32_16x16x32_bf16(afr[ks], bfr, acc[nt], 0, 0, 0);
        }
    }

    // ---- epilogue: C/D col = lane&15, row = (lane>>4)*4 + r ----
    const int rbase = (lane >> 4) * 4;
    #pragma unroll
    for (int nt = 0; nt < 3; ++nt) {
        const int gu = unit0 + nw * 48 + nt * 16 + frow;
        const float bias = (gu < H_INIT) ? bi1[gu] : bd1[gu - H_INIT];
        #pragma unroll
        for (int r = 0; r < 4; ++r) {
            const int item = item0 + mw * 16 + rbase + r;
            P[item * PCOLS + gu] = LAM * (acc[nt][r] + bias);
        }
    }
}

// ---------------------------------------------------------------------------
// K_RK4 (ILP-2): TWO items per wave — two independent serial chains
// interleaved WITHIN one wave (the 2-wave TLP ran in lockstep and hid
// nothing; R16's cross-wave split added barriers and regressed).
// Shared per-wave state: c[], w2m2[], At[] raw, W2sum/Kc (item-independent).
// Per-strand: a[8] (= s*At, precomputed exactly as before -> per-item math
// BIT-IDENTICAL to R17), g[8], s, x. RK4-2 (8 evals), proven error budget.
// Grid 256 x 256thr = 1024 waves; ~100 VGPR, no spill.
// ---------------------------------------------------------------------------
__global__ __launch_bounds__(256) void k_rk4(
    const float* __restrict__ bt,
    const float* __restrict__ At, const float* __restrict__ Ct,
    const float* __restrict__ W2m2t,
    const float* __restrict__ Wi2, const float* __restrict__ bi2,
    const float* __restrict__ bd2,
    const float* __restrict__ P,
    float* __restrict__ out)
{
    const int lane = threadIdx.x & 63;
    const int w    = threadIdx.x >> 6;     // 0..3
    const int iA   = blockIdx.x * 8 + w * 2;
    const int iB   = iA + 1;

    const float* __restrict__ PrA = P + iA * PCOLS;
    const float* __restrict__ PrB = P + iB * PCOLS;
    const float sA = bt[iA];
    const float sB = bt[iB];

    float c[8], w2m2[8], aA[8], aB[8], gA[8], gB[8];
    float w2p = 0.f;
    #pragma unroll
    for (int u = 0; u < 8; ++u) {
        int j = u * 64 + lane;
        float at = At[j];
        aA[u]   = sA * at;                 // == (LAM*sA)*Wd1[j][0], bit-identical to R17
        aB[u]   = sB * at;
        c[u]    = Ct[j];
        w2m2[u] = W2m2t[j];
        w2p    += -0.5f * w2m2[u];         // == Wd2[j], exact
        gA[u]   = PrA[H_INIT + j];
        gB[u]   = PrB[H_INIT + j];
    }
    const float W2sum = wave_total(w2p);
    const float Kc    = W2sum + bd2[0];    // folded  sum(w2) + bd2  (shared)

    // init MLP, both strands interleaved
    float accA0 = 0.f, accA1 = 0.f, accB0 = 0.f, accB1 = 0.f;
    #pragma unroll
    for (int q = 0; q < 4; ++q) {
        int j = q * 64 + lane;
        float wi = Wi2[j];
        float eA = fexp2(PrA[j]);
        float eB = fexp2(PrB[j]);
        float rA = __builtin_amdgcn_rcpf(eA + 1.f);
        float rB = __builtin_amdgcn_rcpf(eB + 1.f);
        float tA = fmaf(-2.f, rA, 1.f);
        float tB = fmaf(-2.f, rB, 1.f);
        if (q & 1) { accA1 = fmaf(wi, tA, accA1); accB1 = fmaf(wi, tB, accB1); }
        else       { accA0 = fmaf(wi, tA, accA0); accB0 = fmaf(wi, tB, accB0); }
    }
    float xA = wave_total(accA0 + accA1) + bi2[0];
    float xB = wave_total(accB0 + accB1) + bi2[0];

    // paired dynamics eval: two independent chains, adjacent instructions
    auto feval2 = [&](float tt, float xvA, float xvB, float& fA, float& fB) {
        float pA0 = 0.f, pA1 = 0.f, pB0 = 0.f, pB1 = 0.f;
        #pragma unroll
        for (int u = 0; u < 8; ++u) {
            float yA = fmaf(aA[u], tt, fmaf(c[u], xvA, gA[u]));
            float yB = fmaf(aB[u], tt, fmaf(c[u], xvB, gB[u]));
            float eA = fexp2(yA);
            float eB = fexp2(yB);
            float rA = __builtin_amdgcn_rcpf(eA + 1.f);
            float rB = __builtin_amdgcn_rcpf(eB + 1.f);
            if (u & 1) { pA1 = fmaf(w2m2[u], rA, pA1); pB1 = fmaf(w2m2[u], rB, pB1); }
            else       { pA0 = fmaf(w2m2[u], rA, pA0); pB0 = fmaf(w2m2[u], rB, pB0); }
        }
        fA = (wave_total(pA0 + pA1) + Kc) * sA;
        fB = (wave_total(pB0 + pB1) + Kc) * sB;
    };

    const float H  = 0.5f;
    const float H2 = 0.25f;
    #pragma unroll
    for (int i = 0; i < 2; ++i) {
        float t = (float)i * H;            // literal after unroll
        float k1A, k1B, k2A, k2B, k3A, k3B, k4A, k4B;
        feval2(t,      xA,                  xB,                  k1A, k1B);
        feval2(t + H2, fmaf(H2, k1A, xA),   fmaf(H2, k1B, xB),   k2A, k2B);
        feval2(t + H2, fmaf(H2, k2A, xA),   fmaf(H2, k2B, xB),   k3A, k3B);
        feval2(t + H,  fmaf(H, k3A, xA),    fmaf(H, k3B, xB),    k4A, k4B);
        xA = xA + (H / 6.f) * (k1A + 2.f * (k2A + k3A) + k4A);
        xB = xB + (H / 6.f) * (k1B + 2.f * (k2B + k3B) + k4B);
    }

    if (lane == 0) { out[iA] = xA; out[iB] = xB; }
}

extern "C" void kernel_launch(void* const* d_in, const int* in_sizes, int n_in,
                              void* d_out, int out_size, void* d_ws, size_t ws_size,
                              hipStream_t stream) {
    const int*   b_i_n = (const int*)d_in[0];
    const float* b_t_n = (const float*)d_in[1];
    const float* U0    = (const float*)d_in[2];
    const float* U1    = (const float*)d_in[3];
    const float* U2    = (const float*)d_in[4];
    const float* Wi1   = (const float*)d_in[5];
    const float* bi1   = (const float*)d_in[6];
    const float* Wi2   = (const float*)d_in[7];
    const float* bi2   = (const float*)d_in[8];
    const float* Wd1   = (const float*)d_in[9];
    const float* bd1   = (const float*)d_in[10];
    const float* Wd2   = (const float*)d_in[11];
    const float* bd2   = (const float*)d_in[12];
    float* outp = (float*)d_out;

    char* ws = (char*)d_ws;
    float* P     = (float*)ws;                        // 6291456 B
    float* At    = (float*)(ws + 6291456);            // 2048 B
    float* Ct    = (float*)(ws + 6293504);            // 2048 B
    float* W2m2t = (float*)(ws + 6295552);            // 2048 B

    k_gemm<<<257, 512, 0, stream>>>(b_i_n, U0, U1, U2, Wi1, bi1, Wd1, bd1, Wd2,
                                    P, At, Ct, W2m2t);
    k_rk4<<<NB / 8, 256, 0, stream>>>(b_t_n, At, Ct, W2m2t, Wi2, bi2, bd2,
                                      P, outp);
}